// Round 1
// baseline (352.871 us; speedup 1.0000x reference)
//
#include <hip/hip_runtime.h>
#include <hip/hip_fp16.h>

#define N_TOK 8192
#define DMODEL 1024
#define HDIM 2048
#define NEXP 8
#define NPAD (N_TOK + NEXP * 128)   // 9216 (each expert segment padded to x128)
#define NTILES (NPAD / 128)         // 72 row tiles max

typedef _Float16 f16;
typedef _Float16 f16x8 __attribute__((ext_vector_type(8)));
typedef float f32x4 __attribute__((ext_vector_type(4)));

__device__ __forceinline__ int swz(int b) { return b ^ ((b >> 3) & 0x70); }

// ---- K1: histogram + padded segment plan (1 block) ----
__global__ void k_plan(const int* __restrict__ ids, int* __restrict__ cursor,
                       int* __restrict__ tile_map) {
    __shared__ int hist[NEXP];
    const int tid = threadIdx.x;
    if (tid < NEXP) hist[tid] = 0;
    __syncthreads();
    for (int t = tid; t < N_TOK; t += 256) atomicAdd(&hist[ids[t]], 1);
    __syncthreads();
    if (tid == 0) {
        int pos = 0, tile = 0;
        for (int e = 0; e < NEXP; ++e) {
            cursor[e] = pos;                       // padded start of segment e
            const int nt = (hist[e] + 127) >> 7;
            for (int i = 0; i < nt; ++i) tile_map[tile++] = e;
            pos += nt * 128;
        }
        for (; tile < NTILES; ++tile) tile_map[tile] = -1;
    }
}

// ---- K2: scatter token indices into padded perm ----
__global__ void k_scatter(const int* __restrict__ ids, int* __restrict__ cursor,
                          int* __restrict__ perm) {
    const int t = blockIdx.x * 256 + threadIdx.x;
    if (t < N_TOK) {
        const int e = ids[t];
        const int pos = atomicAdd(&cursor[e], 1);
        perm[pos] = t;
    }
}

// ---- K3: fp32 -> f16 weight conversion (grid sized exactly) ----
__global__ void k_cvt(const float* __restrict__ src, f16* __restrict__ dst) {
    const size_t i = (size_t)blockIdx.x * 256 + threadIdx.x;  // 8-elem chunk idx
    const float4* s = (const float4*)src + i * 2;
    const float4 a = s[0], b = s[1];
    f16x8 v;
    v[0] = (f16)a.x; v[1] = (f16)a.y; v[2] = (f16)a.z; v[3] = (f16)a.w;
    v[4] = (f16)b.x; v[5] = (f16)b.y; v[6] = (f16)b.z; v[7] = (f16)b.w;
    ((f16x8*)dst)[i] = v;
}

// ---- K4: gather x rows into padded/permuted f16 matrix ----
__global__ void k_gather(const float* __restrict__ x, const int* __restrict__ perm,
                         f16* __restrict__ xp) {
    const int row = blockIdx.x;
    const int tok = perm[row];
    const int c = threadIdx.x;  // 128 threads, one 8-elem chunk each
    f16x8 v;
#pragma unroll
    for (int j = 0; j < 8; ++j) v[j] = (f16)0.f;
    if (tok >= 0) {
        const float4* s = (const float4*)(x + (size_t)tok * DMODEL) + c * 2;
        const float4 a = s[0], b = s[1];
        v[0] = (f16)a.x; v[1] = (f16)a.y; v[2] = (f16)a.z; v[3] = (f16)a.w;
        v[4] = (f16)b.x; v[5] = (f16)b.y; v[6] = (f16)b.z; v[7] = (f16)b.w;
    }
    *((f16x8*)(xp + (size_t)row * DMODEL) + c) = v;
}

// ---- K5: GEMM1 fused gate+up+SwiGLU. 128x128 tile, K=DMODEL, BK=64 ----
template <bool W16>
__global__ __launch_bounds__(256) void k_gemm1(
    const f16* __restrict__ xp, const f16* __restrict__ wg16,
    const f16* __restrict__ wu16, const float* __restrict__ wg32,
    const float* __restrict__ wu32, const int* __restrict__ tile_map,
    f16* __restrict__ hidden) {
    const int rt = blockIdx.y, ct = blockIdx.x;
    const int e = tile_map[rt];
    if (e < 0) return;
    const int tid = threadIdx.x;
    const int lane = tid & 63, wid = tid >> 6;
    const int wm = wid >> 1, wn = wid & 1;
    const int lrow = lane & 15, lk = lane >> 4;
    const int rbase = rt * 128, cbase = ct * 128;

    __shared__ char smem[3 * 128 * 64 * 2];
    char* scA = smem;
    char* scG = smem + 16384;
    char* scU = smem + 32768;

    f32x4 accg[4][4] = {};
    f32x4 accu[4][4] = {};

    const size_t wbase = (size_t)e * HDIM * DMODEL;

    for (int kt = 0; kt < DMODEL / 64; ++kt) {
        const int kbase = kt * 64;
        f16x8 av[4], gv[4], uv[4];
#pragma unroll
        for (int i = 0; i < 4; ++i) {
            const int chunk = tid + i * 256;
            const int row = chunk >> 3, c8 = chunk & 7;
            av[i] = *(const f16x8*)(xp + (size_t)(rbase + row) * DMODEL + kbase + c8 * 8);
            if (W16) {
                gv[i] = *(const f16x8*)(wg16 + wbase + (size_t)(cbase + row) * DMODEL + kbase + c8 * 8);
                uv[i] = *(const f16x8*)(wu16 + wbase + (size_t)(cbase + row) * DMODEL + kbase + c8 * 8);
            } else {
                const float4* gp = (const float4*)(wg32 + wbase + (size_t)(cbase + row) * DMODEL + kbase) + c8 * 2;
                const float4* up = (const float4*)(wu32 + wbase + (size_t)(cbase + row) * DMODEL + kbase) + c8 * 2;
                const float4 g0 = gp[0], g1 = gp[1], u0 = up[0], u1 = up[1];
                gv[i][0] = (f16)g0.x; gv[i][1] = (f16)g0.y; gv[i][2] = (f16)g0.z; gv[i][3] = (f16)g0.w;
                gv[i][4] = (f16)g1.x; gv[i][5] = (f16)g1.y; gv[i][6] = (f16)g1.z; gv[i][7] = (f16)g1.w;
                uv[i][0] = (f16)u0.x; uv[i][1] = (f16)u0.y; uv[i][2] = (f16)u0.z; uv[i][3] = (f16)u0.w;
                uv[i][4] = (f16)u1.x; uv[i][5] = (f16)u1.y; uv[i][6] = (f16)u1.z; uv[i][7] = (f16)u1.w;
            }
        }
        __syncthreads();
#pragma unroll
        for (int i = 0; i < 4; ++i) {
            const int chunk = tid + i * 256;
            const int off = swz(chunk * 16);
            *(f16x8*)(scA + off) = av[i];
            *(f16x8*)(scG + off) = gv[i];
            *(f16x8*)(scU + off) = uv[i];
        }
        __syncthreads();
#pragma unroll
        for (int kk = 0; kk < 2; ++kk) {
            f16x8 af[4], gf[4], uf[4];
#pragma unroll
            for (int m = 0; m < 4; ++m) {
                const int row = wm * 64 + m * 16 + lrow;
                af[m] = *(const f16x8*)(scA + swz(row * 128 + kk * 64 + lk * 16));
            }
#pragma unroll
            for (int n = 0; n < 4; ++n) {
                const int row = wn * 64 + n * 16 + lrow;
                const int off = swz(row * 128 + kk * 64 + lk * 16);
                gf[n] = *(const f16x8*)(scG + off);
                uf[n] = *(const f16x8*)(scU + off);
            }
#pragma unroll
            for (int m = 0; m < 4; ++m)
#pragma unroll
                for (int n = 0; n < 4; ++n) {
                    accg[m][n] = __builtin_amdgcn_mfma_f32_16x16x32_f16(af[m], gf[n], accg[m][n], 0, 0, 0);
                    accu[m][n] = __builtin_amdgcn_mfma_f32_16x16x32_f16(af[m], uf[n], accu[m][n], 0, 0, 0);
                }
        }
    }
    // epilogue: SwiGLU -> hidden (f16)
#pragma unroll
    for (int m = 0; m < 4; ++m) {
#pragma unroll
        for (int n = 0; n < 4; ++n) {
            const int col = cbase + wn * 64 + n * 16 + lrow;
#pragma unroll
            for (int r = 0; r < 4; ++r) {
                const int row = rbase + wm * 64 + m * 16 + lk * 4 + r;
                const float g = accg[m][n][r], u = accu[m][n][r];
                const float h = g / (1.f + __expf(-g)) * u;
                hidden[(size_t)row * HDIM + col] = (f16)h;
            }
        }
    }
}

// ---- K6: GEMM2 (hidden @ Wd^T) + scatter to out ----
template <bool W16>
__global__ __launch_bounds__(256) void k_gemm2(
    const f16* __restrict__ hidden, const f16* __restrict__ wd16,
    const float* __restrict__ wd32, const int* __restrict__ tile_map,
    const int* __restrict__ perm, float* __restrict__ out) {
    const int rt = blockIdx.y, ct = blockIdx.x;
    const int e = tile_map[rt];
    if (e < 0) return;
    const int tid = threadIdx.x;
    const int lane = tid & 63, wid = tid >> 6;
    const int wm = wid >> 1, wn = wid & 1;
    const int lrow = lane & 15, lk = lane >> 4;
    const int rbase = rt * 128, cbase = ct * 128;

    __shared__ char smem[2 * 128 * 64 * 2];
    char* scA = smem;
    char* scB = smem + 16384;

    f32x4 acc[4][4] = {};
    const size_t wbase = (size_t)e * DMODEL * HDIM;

    for (int kt = 0; kt < HDIM / 64; ++kt) {
        const int kbase = kt * 64;
        f16x8 av[4], bv[4];
#pragma unroll
        for (int i = 0; i < 4; ++i) {
            const int chunk = tid + i * 256;
            const int row = chunk >> 3, c8 = chunk & 7;
            av[i] = *(const f16x8*)(hidden + (size_t)(rbase + row) * HDIM + kbase + c8 * 8);
            if (W16) {
                bv[i] = *(const f16x8*)(wd16 + wbase + (size_t)(cbase + row) * HDIM + kbase + c8 * 8);
            } else {
                const float4* bp = (const float4*)(wd32 + wbase + (size_t)(cbase + row) * HDIM + kbase) + c8 * 2;
                const float4 b0 = bp[0], b1 = bp[1];
                bv[i][0] = (f16)b0.x; bv[i][1] = (f16)b0.y; bv[i][2] = (f16)b0.z; bv[i][3] = (f16)b0.w;
                bv[i][4] = (f16)b1.x; bv[i][5] = (f16)b1.y; bv[i][6] = (f16)b1.z; bv[i][7] = (f16)b1.w;
            }
        }
        __syncthreads();
#pragma unroll
        for (int i = 0; i < 4; ++i) {
            const int chunk = tid + i * 256;
            const int off = swz(chunk * 16);
            *(f16x8*)(scA + off) = av[i];
            *(f16x8*)(scB + off) = bv[i];
        }
        __syncthreads();
#pragma unroll
        for (int kk = 0; kk < 2; ++kk) {
            f16x8 af[4], bf[4];
#pragma unroll
            for (int m = 0; m < 4; ++m) {
                const int row = wm * 64 + m * 16 + lrow;
                af[m] = *(const f16x8*)(scA + swz(row * 128 + kk * 64 + lk * 16));
            }
#pragma unroll
            for (int n = 0; n < 4; ++n) {
                const int row = wn * 64 + n * 16 + lrow;
                bf[n] = *(const f16x8*)(scB + swz(row * 128 + kk * 64 + lk * 16));
            }
#pragma unroll
            for (int m = 0; m < 4; ++m)
#pragma unroll
                for (int n = 0; n < 4; ++n)
                    acc[m][n] = __builtin_amdgcn_mfma_f32_16x16x32_f16(af[m], bf[n], acc[m][n], 0, 0, 0);
        }
    }
    // epilogue: scatter rows back to token order (fp32 out)
#pragma unroll
    for (int m = 0; m < 4; ++m) {
        int toks[4];
#pragma unroll
        for (int r = 0; r < 4; ++r) toks[r] = perm[rbase + wm * 64 + m * 16 + lk * 4 + r];
#pragma unroll
        for (int n = 0; n < 4; ++n) {
            const int col = cbase + wn * 64 + n * 16 + lrow;
#pragma unroll
            for (int r = 0; r < 4; ++r)
                if (toks[r] >= 0) out[(size_t)toks[r] * DMODEL + col] = acc[m][n][r];
        }
    }
}

extern "C" void kernel_launch(void* const* d_in, const int* in_sizes, int n_in,
                              void* d_out, int out_size, void* d_ws, size_t ws_size,
                              hipStream_t stream) {
    const float* x = (const float*)d_in[0];
    const float* wg = (const float*)d_in[1];
    const float* wu = (const float*)d_in[2];
    const float* wd = (const float*)d_in[3];
    const int* ids = (const int*)d_in[4];
    float* out = (float*)d_out;

    char* ws = (char*)d_ws;
    int* cursor = (int*)ws;               // 8 ints
    int* tile_map = (int*)(ws + 64);      // 72 ints
    int* perm = (int*)(ws + 4096);        // NPAD ints
    const size_t XP_OFF = 65536;
    const size_t XP_BYTES = (size_t)NPAD * DMODEL * 2;    // 18.9 MB
    const size_t HID_OFF = XP_OFF + XP_BYTES;
    const size_t HID_BYTES = (size_t)NPAD * HDIM * 2;     // 37.7 MB
    const size_t WG_OFF = HID_OFF + HID_BYTES;
    const size_t W_BYTES = (size_t)NEXP * HDIM * DMODEL * 2;  // 33.6 MB each
    f16* xp = (f16*)(ws + XP_OFF);
    f16* hidden = (f16*)(ws + HID_OFF);
    f16* wg16 = (f16*)(ws + WG_OFF);
    f16* wu16 = (f16*)(ws + WG_OFF + W_BYTES);
    f16* wd16 = (f16*)(ws + WG_OFF + 2 * W_BYTES);
    const bool w16 = ws_size >= WG_OFF + 3 * W_BYTES;     // ~157.4 MB

    hipMemsetAsync(perm, 0xFF, (size_t)NPAD * 4, stream);
    k_plan<<<1, 256, 0, stream>>>(ids, cursor, tile_map);
    k_scatter<<<N_TOK / 256, 256, 0, stream>>>(ids, cursor, perm);
    if (w16) {
        k_cvt<<<8192, 256, 0, stream>>>(wg, wg16);
        k_cvt<<<8192, 256, 0, stream>>>(wu, wu16);
        k_cvt<<<8192, 256, 0, stream>>>(wd, wd16);
    }
    k_gather<<<NPAD, 128, 0, stream>>>(x, perm, xp);
    if (w16) {
        k_gemm1<true><<<dim3(HDIM / 128, NTILES), 256, 0, stream>>>(xp, wg16, wu16, nullptr, nullptr, tile_map, hidden);
        k_gemm2<true><<<dim3(DMODEL / 128, NTILES), 256, 0, stream>>>(hidden, wd16, nullptr, tile_map, perm, out);
    } else {
        k_gemm1<false><<<dim3(HDIM / 128, NTILES), 256, 0, stream>>>(xp, nullptr, nullptr, wg, wu, tile_map, hidden);
        k_gemm2<false><<<dim3(DMODEL / 128, NTILES), 256, 0, stream>>>(hidden, nullptr, wd, tile_map, perm, out);
    }
}

// Round 3
// 339.974 us; speedup vs baseline: 1.0379x; 1.0379x over previous
//
#include <hip/hip_runtime.h>
#include <hip/hip_fp16.h>

#define N_TOK 8192
#define DMODEL 1024
#define HDIM 2048
#define NEXP 8
#define NGU (2 * HDIM)              // 4096 interleaved gate/up cols
#define NPAD (N_TOK + NEXP * 128)   // 9216
#define NTILES (NPAD / 128)         // 72

typedef _Float16 f16;
typedef _Float16 f16x8 __attribute__((ext_vector_type(8)));
typedef float f32x4 __attribute__((ext_vector_type(4)));

// async global->LDS, 16B per lane; LDS dest = wave-uniform base + lane*16
__device__ __forceinline__ void gload16(const void* g, void* l) {
    __builtin_amdgcn_global_load_lds(
        (const __attribute__((address_space(1))) void*)g,
        (__attribute__((address_space(3))) void*)l, 16, 0, 0);
}

// stage a 128x64 f16 tile (row stride src_stride elems) into linear LDS [128][64]
// chunk = 1KB = 8 rows x 128B; lane l -> row chunk*8 + (l>>3), col (l&7)*8 elems
__device__ __forceinline__ void stage_tile(const f16* src, size_t src_stride,
                                           char* lds, int wid, int lane) {
#pragma unroll
    for (int i = 0; i < 4; ++i) {
        const int chunk = wid * 4 + i;                 // 16 chunks of 1KB
        const int row = chunk * 8 + (lane >> 3);
        const f16* g = src + (size_t)row * src_stride + (lane & 7) * 8;
        gload16(g, lds + chunk * 1024);
    }
}

// ---- K1: histogram + padded segment plan (1 block) ----
__global__ void k_plan(const int* __restrict__ ids, int* __restrict__ cursor,
                       int* __restrict__ tile_map) {
    __shared__ int hist[NEXP];
    const int tid = threadIdx.x;
    if (tid < NEXP) hist[tid] = 0;
    __syncthreads();
    for (int t = tid; t < N_TOK; t += 256) atomicAdd(&hist[ids[t]], 1);
    __syncthreads();
    if (tid == 0) {
        int pos = 0, tile = 0;
        for (int e = 0; e < NEXP; ++e) {
            cursor[e] = pos;
            const int nt = (hist[e] + 127) >> 7;
            for (int i = 0; i < nt; ++i) tile_map[tile++] = e;
            pos += nt * 128;
        }
        for (; tile < NTILES; ++tile) tile_map[tile] = -1;
    }
}

// ---- K2: scatter token indices into padded perm ----
__global__ void k_scatter(const int* __restrict__ ids, int* __restrict__ cursor,
                          int* __restrict__ perm) {
    const int t = blockIdx.x * 256 + threadIdx.x;
    if (t < N_TOK) {
        const int pos = atomicAdd(&cursor[ids[t]], 1);
        perm[pos] = t;
    }
}

// ---- K3a: fp32 -> f16 plain convert (for wd) ----
__global__ void k_cvt(const float* __restrict__ src, f16* __restrict__ dst) {
    const size_t i = (size_t)blockIdx.x * 256 + threadIdx.x;
    const float4* s = (const float4*)src + i * 2;
    const float4 a = s[0], b = s[1];
    f16x8 v;
    v[0] = (f16)a.x; v[1] = (f16)a.y; v[2] = (f16)a.z; v[3] = (f16)a.w;
    v[4] = (f16)b.x; v[5] = (f16)b.y; v[6] = (f16)b.z; v[7] = (f16)b.w;
    ((f16x8*)dst)[i] = v;
}

// ---- K3b: gate/up -> interleaved f16 [E][4096][1024]
// col c: h = (c>>5)*16 + (c&15); (c>>4)&1 = 0 gate, 1 up ----
__global__ void k_cvt_gu(const float* __restrict__ wg, const float* __restrict__ wu,
                         f16* __restrict__ wgu) {
    const int R = blockIdx.x;                 // 0..NEXP*NGU-1
    const int e = R >> 12, c = R & (NGU - 1);
    const int h = ((c >> 5) << 4) | (c & 15);
    const float* src = (((c >> 4) & 1) ? wu : wg) + ((size_t)e * HDIM + h) * DMODEL;
    f16* dst = wgu + (size_t)R * DMODEL;
    const int t = threadIdx.x;                // 128 threads x 8 elems
    const float4* s = (const float4*)src + t * 2;
    const float4 a = s[0], b = s[1];
    f16x8 v;
    v[0] = (f16)a.x; v[1] = (f16)a.y; v[2] = (f16)a.z; v[3] = (f16)a.w;
    v[4] = (f16)b.x; v[5] = (f16)b.y; v[6] = (f16)b.z; v[7] = (f16)b.w;
    ((f16x8*)dst)[t] = v;
}

// ---- K4: gather x rows into padded/permuted f16 matrix ----
__global__ void k_gather(const float* __restrict__ x, const int* __restrict__ perm,
                         f16* __restrict__ xp) {
    const int row = blockIdx.x;
    const int tok = perm[row];
    const int c = threadIdx.x;
    f16x8 v;
#pragma unroll
    for (int j = 0; j < 8; ++j) v[j] = (f16)0.f;
    if (tok >= 0) {
        const float4* s = (const float4*)(x + (size_t)tok * DMODEL) + c * 2;
        const float4 a = s[0], b = s[1];
        v[0] = (f16)a.x; v[1] = (f16)a.y; v[2] = (f16)a.z; v[3] = (f16)a.w;
        v[4] = (f16)b.x; v[5] = (f16)b.y; v[6] = (f16)b.z; v[7] = (f16)b.w;
    }
    *((f16x8*)(xp + (size_t)row * DMODEL) + c) = v;
}

// ---- K5: GEMM1 (xp @ wgu^T) + SwiGLU pairing -> hidden. m97 structure. ----
__global__ __launch_bounds__(256) void k_gemm1(
    const f16* __restrict__ xp, const f16* __restrict__ wgu,
    const int* __restrict__ tile_map, f16* __restrict__ hidden) {
    const int rt = blockIdx.y, ct = blockIdx.x;
    const int e = tile_map[rt];
    if (e < 0) return;
    const int tid = threadIdx.x;
    const int lane = tid & 63, wid = tid >> 6;
    const int wm = wid >> 1, wn = wid & 1;
    const int lrow = lane & 15, lk = lane >> 4;
    const int rbase = rt * 128, cbase = ct * 128;

    __shared__ char smem[32768];
    char* sA = smem;
    char* sB = smem + 16384;

    const f16* asrc = xp + (size_t)rbase * DMODEL;
    const f16* bsrc = wgu + (size_t)e * NGU * DMODEL + (size_t)cbase * DMODEL;

    f32x4 acc[4][4] = {};

    for (int kt = 0; kt < DMODEL / 64; ++kt) {
        const int kbase = kt * 64;
        stage_tile(asrc + kbase, DMODEL, sA, wid, lane);
        stage_tile(bsrc + kbase, DMODEL, sB, wid, lane);
        __syncthreads();   // compiler emits vmcnt(0) drain before barrier
#pragma unroll
        for (int kk = 0; kk < 2; ++kk) {
            f16x8 af[4], bf[4];
#pragma unroll
            for (int m = 0; m < 4; ++m)
                af[m] = *(const f16x8*)(sA + (wm * 64 + m * 16 + lrow) * 128 + kk * 64 + lk * 16);
#pragma unroll
            for (int n = 0; n < 4; ++n)
                bf[n] = *(const f16x8*)(sB + (wn * 64 + n * 16 + lrow) * 128 + kk * 64 + lk * 16);
#pragma unroll
            for (int m = 0; m < 4; ++m)
#pragma unroll
                for (int n = 0; n < 4; ++n)
                    acc[m][n] = __builtin_amdgcn_mfma_f32_16x16x32_f16(af[m], bf[n], acc[m][n], 0, 0, 0);
        }
        __syncthreads();
    }
    // epilogue: pair (gate,up) frags -> silu(g)*u -> hidden f16
#pragma unroll
    for (int m = 0; m < 4; ++m) {
#pragma unroll
        for (int np = 0; np < 2; ++np) {
            const int ng = np * 2, nu = ng + 1;
            const int cblock = cbase + wn * 64 + ng * 16;       // gate block (bit4==0)
            const int h = ((cblock >> 5) << 4) + lrow;
#pragma unroll
            for (int r = 0; r < 4; ++r) {
                const int row = rbase + wm * 64 + m * 16 + lk * 4 + r;
                const float g = acc[m][ng][r], u = acc[m][nu][r];
                const float hv = g / (1.f + __expf(-g)) * u;
                hidden[(size_t)row * HDIM + h] = (f16)hv;
            }
        }
    }
}

// ---- K6: GEMM2 (hidden @ wd^T) + scatter to out. m97 structure. ----
__global__ __launch_bounds__(256) void k_gemm2(
    const f16* __restrict__ hidden, const f16* __restrict__ wd16,
    const int* __restrict__ tile_map, const int* __restrict__ perm,
    float* __restrict__ out) {
    const int rt = blockIdx.y, ct = blockIdx.x;
    const int e = tile_map[rt];
    if (e < 0) return;
    const int tid = threadIdx.x;
    const int lane = tid & 63, wid = tid >> 6;
    const int wm = wid >> 1, wn = wid & 1;
    const int lrow = lane & 15, lk = lane >> 4;
    const int rbase = rt * 128, cbase = ct * 128;

    __shared__ char smem[32768];
    char* sA = smem;
    char* sB = smem + 16384;

    const f16* asrc = hidden + (size_t)rbase * HDIM;
    const f16* bsrc = wd16 + (size_t)e * DMODEL * HDIM + (size_t)cbase * HDIM;

    f32x4 acc[4][4] = {};

    for (int kt = 0; kt < HDIM / 64; ++kt) {
        const int kbase = kt * 64;
        stage_tile(asrc + kbase, HDIM, sA, wid, lane);
        stage_tile(bsrc + kbase, HDIM, sB, wid, lane);
        __syncthreads();
#pragma unroll
        for (int kk = 0; kk < 2; ++kk) {
            f16x8 af[4], bf[4];
#pragma unroll
            for (int m = 0; m < 4; ++m)
                af[m] = *(const f16x8*)(sA + (wm * 64 + m * 16 + lrow) * 128 + kk * 64 + lk * 16);
#pragma unroll
            for (int n = 0; n < 4; ++n)
                bf[n] = *(const f16x8*)(sB + (wn * 64 + n * 16 + lrow) * 128 + kk * 64 + lk * 16);
#pragma unroll
            for (int m = 0; m < 4; ++m)
#pragma unroll
                for (int n = 0; n < 4; ++n)
                    acc[m][n] = __builtin_amdgcn_mfma_f32_16x16x32_f16(af[m], bf[n], acc[m][n], 0, 0, 0);
        }
        __syncthreads();
    }
    // epilogue: scatter rows back to token order (fp32 out)
#pragma unroll
    for (int m = 0; m < 4; ++m) {
        int toks[4];
#pragma unroll
        for (int r = 0; r < 4; ++r) toks[r] = perm[rbase + wm * 64 + m * 16 + lk * 4 + r];
#pragma unroll
        for (int n = 0; n < 4; ++n) {
            const int col = cbase + wn * 64 + n * 16 + lrow;
#pragma unroll
            for (int r = 0; r < 4; ++r)
                if (toks[r] >= 0) out[(size_t)toks[r] * DMODEL + col] = acc[m][n][r];
        }
    }
}

extern "C" void kernel_launch(void* const* d_in, const int* in_sizes, int n_in,
                              void* d_out, int out_size, void* d_ws, size_t ws_size,
                              hipStream_t stream) {
    const float* x = (const float*)d_in[0];
    const float* wg = (const float*)d_in[1];
    const float* wu = (const float*)d_in[2];
    const float* wd = (const float*)d_in[3];
    const int* ids = (const int*)d_in[4];
    float* out = (float*)d_out;

    char* ws = (char*)d_ws;
    int* cursor = (int*)ws;
    int* tile_map = (int*)(ws + 64);
    int* perm = (int*)(ws + 4096);
    const size_t XP_OFF = 65536;
    const size_t XP_BYTES = (size_t)NPAD * DMODEL * 2;          // 18.9 MB
    const size_t HID_OFF = XP_OFF + XP_BYTES;
    const size_t HID_BYTES = (size_t)NPAD * HDIM * 2;           // 37.7 MB
    const size_t WGU_OFF = HID_OFF + HID_BYTES;
    const size_t WGU_BYTES = (size_t)NEXP * NGU * DMODEL * 2;   // 67.1 MB
    const size_t WD_OFF = WGU_OFF + WGU_BYTES;
    const size_t WD_BYTES = (size_t)NEXP * DMODEL * HDIM * 2;   // 33.6 MB

    f16* xp = (f16*)(ws + XP_OFF);
    f16* hidden = (f16*)(ws + HID_OFF);
    f16* wgu16 = (f16*)(ws + WGU_OFF);
    f16* wd16 = (f16*)(ws + WD_OFF);

    hipMemsetAsync(perm, 0xFF, (size_t)NPAD * 4, stream);
    k_plan<<<1, 256, 0, stream>>>(ids, cursor, tile_map);
    k_scatter<<<N_TOK / 256, 256, 0, stream>>>(ids, cursor, perm);
    k_cvt_gu<<<NEXP * NGU, 128, 0, stream>>>(wg, wu, wgu16);
    k_cvt<<<8192, 256, 0, stream>>>(wd, wd16);
    k_gather<<<NPAD, 128, 0, stream>>>(x, perm, xp);
    k_gemm1<<<dim3(NGU / 128, NTILES), 256, 0, stream>>>(xp, wgu16, tile_map, hidden);
    k_gemm2<<<dim3(DMODEL / 128, NTILES), 256, 0, stream>>>(hidden, wd16, tile_map, perm, out);
}

// Round 4
// 278.176 us; speedup vs baseline: 1.2685x; 1.2222x over previous
//
#include <hip/hip_runtime.h>
#include <hip/hip_fp16.h>

#define N_TOK 8192
#define DMODEL 1024
#define HDIM 2048
#define NEXP 8
#define NGU (2 * HDIM)               // 4096 interleaved gate/up cols
#define NPAD (N_TOK + NEXP * 256)    // 10240 (expert segments padded to x256)
#define NTILES (NPAD / 256)          // 40

typedef _Float16 f16;
typedef _Float16 f16x8 __attribute__((ext_vector_type(8)));
typedef float f32x4 __attribute__((ext_vector_type(4)));

#define BARRIER() do { __builtin_amdgcn_s_barrier(); __builtin_amdgcn_sched_barrier(0); } while (0)
#define WAIT_LGKM0() do { asm volatile("s_waitcnt lgkmcnt(0)" ::: "memory"); __builtin_amdgcn_sched_barrier(0); } while (0)
#define WAIT_VM(n) do { asm volatile("s_waitcnt vmcnt(" #n ")" ::: "memory"); __builtin_amdgcn_sched_barrier(0); } while (0)

__device__ __forceinline__ void gload16(const void* g, void* l) {
    __builtin_amdgcn_global_load_lds(
        (const __attribute__((address_space(1))) void*)g,
        (__attribute__((address_space(3))) void*)l, 16, 0, 0);
}

// ---- K1: histogram + padded (x256) segment plan ----
__global__ void k_plan(const int* __restrict__ ids, int* __restrict__ cursor,
                       int* __restrict__ tile_map) {
    __shared__ int hist[NEXP];
    const int tid = threadIdx.x;
    if (tid < NEXP) hist[tid] = 0;
    __syncthreads();
    for (int t = tid; t < N_TOK; t += 256) atomicAdd(&hist[ids[t]], 1);
    __syncthreads();
    if (tid == 0) {
        int pos = 0, tile = 0;
        for (int e = 0; e < NEXP; ++e) {
            cursor[e] = pos;
            const int nt = (hist[e] + 255) >> 8;
            for (int i = 0; i < nt; ++i) tile_map[tile++] = e;
            pos += nt * 256;
        }
        for (; tile < NTILES; ++tile) tile_map[tile] = -1;
    }
}

// ---- K2: scatter token indices into padded perm ----
__global__ void k_scatter(const int* __restrict__ ids, int* __restrict__ cursor,
                          int* __restrict__ perm) {
    const int t = blockIdx.x * 256 + threadIdx.x;
    if (t < N_TOK) {
        const int pos = atomicAdd(&cursor[ids[t]], 1);
        perm[pos] = t;
    }
}

// ---- K3a: fp32 -> f16 plain convert (for wd) ----
__global__ void k_cvt(const float* __restrict__ src, f16* __restrict__ dst) {
    const size_t i = (size_t)blockIdx.x * 256 + threadIdx.x;
    const float4* s = (const float4*)src + i * 2;
    const float4 a = s[0], b = s[1];
    f16x8 v;
    v[0] = (f16)a.x; v[1] = (f16)a.y; v[2] = (f16)a.z; v[3] = (f16)a.w;
    v[4] = (f16)b.x; v[5] = (f16)b.y; v[6] = (f16)b.z; v[7] = (f16)b.w;
    ((f16x8*)dst)[i] = v;
}

// ---- K3b: gate/up -> interleaved f16 [E][4096][1024] ----
__global__ void k_cvt_gu(const float* __restrict__ wg, const float* __restrict__ wu,
                         f16* __restrict__ wgu) {
    const int R = blockIdx.x;
    const int e = R >> 12, c = R & (NGU - 1);
    const int h = ((c >> 5) << 4) | (c & 15);
    const float* src = (((c >> 4) & 1) ? wu : wg) + ((size_t)e * HDIM + h) * DMODEL;
    f16* dst = wgu + (size_t)R * DMODEL;
    const int t = threadIdx.x;
    const float4* s = (const float4*)src + t * 2;
    const float4 a = s[0], b = s[1];
    f16x8 v;
    v[0] = (f16)a.x; v[1] = (f16)a.y; v[2] = (f16)a.z; v[3] = (f16)a.w;
    v[4] = (f16)b.x; v[5] = (f16)b.y; v[6] = (f16)b.z; v[7] = (f16)b.w;
    ((f16x8*)dst)[t] = v;
}

// ---- K4: gather x rows into padded/permuted f16 matrix ----
__global__ void k_gather(const float* __restrict__ x, const int* __restrict__ perm,
                         f16* __restrict__ xp) {
    const int row = blockIdx.x;
    const int tok = perm[row];
    const int c = threadIdx.x;
    f16x8 v;
#pragma unroll
    for (int j = 0; j < 8; ++j) v[j] = (f16)0.f;
    if (tok >= 0) {
        const float4* s = (const float4*)(x + (size_t)tok * DMODEL) + c * 2;
        const float4 a = s[0], b = s[1];
        v[0] = (f16)a.x; v[1] = (f16)a.y; v[2] = (f16)a.z; v[3] = (f16)a.w;
        v[4] = (f16)b.x; v[5] = (f16)b.y; v[6] = (f16)b.z; v[7] = (f16)b.w;
    }
    *((f16x8*)(xp + (size_t)row * DMODEL) + c) = v;
}

// ======== 256x256 8-phase GEMM core (8 waves, BK=64, dbuf 8 half-slots) ========
// Slot layout in 128KB LDS: [parity][h] h=0:A0 1:A1 2:B0 3:B1, 16KB each.
// Half-tile = 128 rows x 64 f16, row = 128B. XOR swizzle: 16B slot ^= (row&7),
// applied on the GLOBAL source (linear gload_lds dest) and on ds_read addr.
// Schedule per K-tile kt, phases q=0..3 (quadrant q = A rows q*32..q*32+31):
//   q0: read B(all 8 frags)+A(q0), stage A0(kt+1)
//   q1: read A(q1), stage A1(kt+1)
//   q2: read A(q2), stage B0(kt+2)
//   q3: read A(q3), vmcnt(2), stage B1(kt+2)
//   each phase: barrier; lgkmcnt(0); setprio(1); 16 MFMA; setprio(0); barrier
// Race-freedom: each slot's stage issue is >=1 barrier after its last read.

#define GEMM_CORE(NKT_, STRIDE_)                                                      \
    const int tid = threadIdx.x;                                                      \
    const int lane = tid & 63, wid = tid >> 6;                                        \
    const int wm = wid >> 2, wn = wid & 3;                                            \
    const int lrow = lane & 15, lk = lane >> 4;                                       \
    __shared__ char smem[131072];                                                     \
    const int scol = (lane & 7) ^ (lane >> 3);                                        \
    const int xs0 = ((lk) ^ (lrow & 7)) * 16;                                         \
    const int xs1 = ((4 + lk) ^ (lrow & 7)) * 16;                                     \
    f32x4 acc[8][4] = {};                                                             \
    auto stage = [&](int h, int kt2) {                                                \
        const f16* base = (h < 2) ? (asrc + (size_t)(h * 128) * STRIDE_)              \
                                  : (bsrc + (size_t)((h - 2) * 128) * STRIDE_);       \
        char* dst = smem + ((kt2 & 1) * 4 + h) * 16384 + wid * 1024;                  \
        const int kb = kt2 * 64;                                                      \
        _Pragma("unroll")                                                             \
        for (int pass = 0; pass < 2; ++pass) {                                        \
            const int row = pass * 64 + wid * 8 + (lane >> 3);                        \
            gload16(base + (size_t)row * STRIDE_ + kb + scol * 8, dst + pass * 8192); \
        }                                                                             \
    };                                                                                \
    /* prologue: A0,A1,B0,B1(k0), B0,B1(k1) -> vmcnt(4) */                            \
    stage(0, 0); stage(1, 0); stage(2, 0); stage(3, 0);                               \
    stage(2, 1); stage(3, 1);                                                         \
    WAIT_VM(4);                                                                       \
    BARRIER();                                                                        \
    f16x8 b[4][2];                                                                    \
    for (int kt = 0; kt < NKT_; ++kt) {                                               \
        char* bufA = smem + ((kt & 1) * 4 + wm) * 16384;                              \
        char* bufB = smem + ((kt & 1) * 4 + 2 + (wn >> 1)) * 16384;                   \
        const int brow = (wn & 1) * 64;                                               \
        _Pragma("unroll")                                                             \
        for (int q = 0; q < 4; ++q) {                                                 \
            f16x8 a[2][2];                                                            \
            _Pragma("unroll")                                                         \
            for (int mi = 0; mi < 2; ++mi) {                                          \
                const int r = q * 32 + mi * 16 + lrow;                                \
                a[mi][0] = *(const f16x8*)(bufA + r * 128 + xs0);                     \
                a[mi][1] = *(const f16x8*)(bufA + r * 128 + xs1);                     \
            }                                                                         \
            if (q == 0) {                                                             \
                _Pragma("unroll")                                                     \
                for (int n = 0; n < 4; ++n) {                                         \
                    const int r = brow + n * 16 + lrow;                               \
                    b[n][0] = *(const f16x8*)(bufB + r * 128 + xs0);                  \
                    b[n][1] = *(const f16x8*)(bufB + r * 128 + xs1);                  \
                }                                                                     \
            }                                                                         \
            if (q == 0 && kt + 1 < NKT_) stage(0, kt + 1);                            \
            if (q == 1 && kt + 1 < NKT_) stage(1, kt + 1);                            \
            if (q == 2 && kt + 2 < NKT_) stage(2, kt + 2);                            \
            if (q == 3) {                                                             \
                if (kt + 2 < NKT_) { WAIT_VM(2); stage(3, kt + 2); }                  \
                else { WAIT_VM(0); }                                                  \
            }                                                                         \
            BARRIER();                                                                \
            WAIT_LGKM0();                                                             \
            __builtin_amdgcn_s_setprio(1);                                            \
            _Pragma("unroll")                                                         \
            for (int mi = 0; mi < 2; ++mi)                                            \
                _Pragma("unroll")                                                     \
                for (int n = 0; n < 4; ++n) {                                         \
                    acc[q * 2 + mi][n] = __builtin_amdgcn_mfma_f32_16x16x32_f16(      \
                        a[mi][0], b[n][0], acc[q * 2 + mi][n], 0, 0, 0);              \
                    acc[q * 2 + mi][n] = __builtin_amdgcn_mfma_f32_16x16x32_f16(      \
                        a[mi][1], b[n][1], acc[q * 2 + mi][n], 0, 0, 0);              \
                }                                                                     \
            __builtin_amdgcn_s_setprio(0);                                            \
            BARRIER();                                                                \
        }                                                                             \
    }

// ---- K5: GEMM1 (xp @ wgu^T) + SwiGLU -> hidden ----
__global__ __launch_bounds__(512, 2) void k_gemm1(
    const f16* __restrict__ xp, const f16* __restrict__ wgu,
    const int* __restrict__ tile_map, f16* __restrict__ hidden) {
    const int rt = blockIdx.y, ct = blockIdx.x;
    const int e = tile_map[rt];
    if (e < 0) return;
    const int rbase = rt * 256, cbase = ct * 256;
    const f16* asrc = xp + (size_t)rbase * DMODEL;
    const f16* bsrc = wgu + (size_t)e * NGU * DMODEL + (size_t)cbase * DMODEL;

    GEMM_CORE(16, DMODEL)

    // epilogue: pair (gate,up) frags -> silu(g)*u -> hidden f16
#pragma unroll
    for (int mf = 0; mf < 8; ++mf) {
#pragma unroll
        for (int pair = 0; pair < 2; ++pair) {
            const int ng = pair * 2, nu = ng + 1;
            const int cblock = cbase + wn * 64 + ng * 16;   // bit4==0: gate block
            const int h = ((cblock >> 5) << 4) + lrow;
#pragma unroll
            for (int r = 0; r < 4; ++r) {
                const int row = rbase + wm * 128 + mf * 16 + lk * 4 + r;
                const float g = acc[mf][ng][r], u = acc[mf][nu][r];
                const float hv = g / (1.f + __expf(-g)) * u;
                hidden[(size_t)row * HDIM + h] = (f16)hv;
            }
        }
    }
}

// ---- K6: GEMM2 (hidden @ wd^T) + scatter to out ----
__global__ __launch_bounds__(512, 2) void k_gemm2(
    const f16* __restrict__ hidden, const f16* __restrict__ wd16,
    const int* __restrict__ tile_map, const int* __restrict__ perm,
    float* __restrict__ out) {
    const int rt = blockIdx.y, ct = blockIdx.x;
    const int e = tile_map[rt];
    if (e < 0) return;
    const int rbase = rt * 256, cbase = ct * 256;
    const f16* asrc = hidden + (size_t)rbase * HDIM;
    const f16* bsrc = wd16 + (size_t)e * DMODEL * HDIM + (size_t)cbase * HDIM;

    GEMM_CORE(32, HDIM)

    // epilogue: scatter rows back to token order (fp32 out)
#pragma unroll
    for (int mf = 0; mf < 8; ++mf) {
        int toks[4];
#pragma unroll
        for (int r = 0; r < 4; ++r)
            toks[r] = perm[rbase + wm * 128 + mf * 16 + lk * 4 + r];
#pragma unroll
        for (int n = 0; n < 4; ++n) {
            const int col = cbase + wn * 64 + n * 16 + lrow;
#pragma unroll
            for (int r = 0; r < 4; ++r)
                if (toks[r] >= 0) out[(size_t)toks[r] * DMODEL + col] = acc[mf][n][r];
        }
    }
}

extern "C" void kernel_launch(void* const* d_in, const int* in_sizes, int n_in,
                              void* d_out, int out_size, void* d_ws, size_t ws_size,
                              hipStream_t stream) {
    const float* x = (const float*)d_in[0];
    const float* wg = (const float*)d_in[1];
    const float* wu = (const float*)d_in[2];
    const float* wd = (const float*)d_in[3];
    const int* ids = (const int*)d_in[4];
    float* out = (float*)d_out;

    char* ws = (char*)d_ws;
    int* cursor = (int*)ws;
    int* tile_map = (int*)(ws + 64);
    int* perm = (int*)(ws + 4096);
    const size_t XP_OFF = 65536;
    const size_t XP_BYTES = (size_t)NPAD * DMODEL * 2;          // 21.0 MB
    const size_t HID_OFF = XP_OFF + XP_BYTES;
    const size_t HID_BYTES = (size_t)NPAD * HDIM * 2;           // 41.9 MB
    const size_t WGU_OFF = HID_OFF + HID_BYTES;
    // wd16 aliases onto wgu (dead after GEMM1); cvt_wd runs after GEMM1.

    f16* xp = (f16*)(ws + XP_OFF);
    f16* hidden = (f16*)(ws + HID_OFF);
    f16* wgu16 = (f16*)(ws + WGU_OFF);
    f16* wd16 = (f16*)(ws + WGU_OFF);

    hipMemsetAsync(perm, 0xFF, (size_t)NPAD * 4, stream);
    k_plan<<<1, 256, 0, stream>>>(ids, cursor, tile_map);
    k_scatter<<<N_TOK / 256, 256, 0, stream>>>(ids, cursor, perm);
    k_gather<<<NPAD, 128, 0, stream>>>(x, perm, xp);
    k_cvt_gu<<<NEXP * NGU, 128, 0, stream>>>(wg, wu, wgu16);
    k_gemm1<<<dim3(NGU / 256, NTILES), 512, 0, stream>>>(xp, wgu16, tile_map, hidden);
    k_cvt<<<8192, 256, 0, stream>>>(wd, wd16);   // into aliased region, after GEMM1
    k_gemm2<<<dim3(DMODEL / 256, NTILES), 512, 0, stream>>>(hidden, wd16, tile_map, perm, out);
}